// Round 3
// baseline (1499.126 us; speedup 1.0000x reference)
//
#include <hip/hip_runtime.h>
#include <cstddef>

#define T_LEN 4096
#define EMB 768
#define NH 12
#define HD 64
#define WIN 512

// ---------------- GEMM f32, 128x128 tile, 8x8 microtile, up to 3 B/C pairs via blockIdx.z.
// Register-prefetch double buffer: next k-slice loads issue right after the staging barrier,
// hiding global latency under the 16x64-FMA inner loop.
#define GBM 128
#define GBN 128
#define GBK 16

__global__ __launch_bounds__(256) void gemm3_f32(const float* __restrict__ A,
                                                 const float* __restrict__ B0,
                                                 const float* __restrict__ B1,
                                                 const float* __restrict__ B2,
                                                 float* __restrict__ C0,
                                                 float* __restrict__ C1,
                                                 float* __restrict__ C2,
                                                 int M, int N, int K) {
    __shared__ float As[GBK][GBM + 4];   // A transposed: [k][m]
    __shared__ float Bs[GBK][GBN + 4];   // B row-major:  [k][n]
    const int tid = threadIdx.x;
    const int bm = blockIdx.y * GBM;
    const int bn = blockIdx.x * GBN;
    const float* __restrict__ B = (blockIdx.z == 0) ? B0 : (blockIdx.z == 1) ? B1 : B2;
    float* __restrict__ C = (blockIdx.z == 0) ? C0 : (blockIdx.z == 1) ? C1 : C2;

    const int ty = (tid >> 4) << 2;      // row frag base: rows {ty..ty+3, ty+64..ty+67}
    const int tx = (tid & 15) << 2;      // col frag base: cols {tx..tx+3, tx+64..tx+67}

    const int ar = tid >> 1;             // staging A: row 0..127
    const int ac = (tid & 1) << 3;       // staging A: k base 0 or 8
    const int br = tid >> 4;             // staging B: k row 0..15
    const int bc = (tid & 15) << 3;      // staging B: col base 0..120

    float acc[8][8] = {};

    // preload k0 = 0
    float4 pa0 = *(const float4*)&A[(size_t)(bm + ar) * K + ac];
    float4 pa1 = *(const float4*)&A[(size_t)(bm + ar) * K + ac + 4];
    float4 pb0 = *(const float4*)&B[(size_t)br * N + bn + bc];
    float4 pb1 = *(const float4*)&B[(size_t)br * N + bn + bc + 4];

    for (int k0 = 0; k0 < K; k0 += GBK) {
        As[ac + 0][ar] = pa0.x; As[ac + 1][ar] = pa0.y; As[ac + 2][ar] = pa0.z; As[ac + 3][ar] = pa0.w;
        As[ac + 4][ar] = pa1.x; As[ac + 5][ar] = pa1.y; As[ac + 6][ar] = pa1.z; As[ac + 7][ar] = pa1.w;
        *(float4*)&Bs[br][bc]     = pb0;
        *(float4*)&Bs[br][bc + 4] = pb1;
        __syncthreads();
        if (k0 + GBK < K) {   // prefetch next slice; latency hides under the FMA loop
            pa0 = *(const float4*)&A[(size_t)(bm + ar) * K + k0 + GBK + ac];
            pa1 = *(const float4*)&A[(size_t)(bm + ar) * K + k0 + GBK + ac + 4];
            pb0 = *(const float4*)&B[(size_t)(k0 + GBK + br) * N + bn + bc];
            pb1 = *(const float4*)&B[(size_t)(k0 + GBK + br) * N + bn + bc + 4];
        }
#pragma unroll
        for (int k = 0; k < GBK; ++k) {
            const float4 a0v = *(const float4*)&As[k][ty];
            const float4 a1v = *(const float4*)&As[k][ty + 64];
            const float4 b0v = *(const float4*)&Bs[k][tx];
            const float4 b1v = *(const float4*)&Bs[k][tx + 64];
            const float av[8] = {a0v.x, a0v.y, a0v.z, a0v.w, a1v.x, a1v.y, a1v.z, a1v.w};
            const float bv[8] = {b0v.x, b0v.y, b0v.z, b0v.w, b1v.x, b1v.y, b1v.z, b1v.w};
#pragma unroll
            for (int i = 0; i < 8; ++i)
#pragma unroll
                for (int j = 0; j < 8; ++j)
                    acc[i][j] += av[i] * bv[j];
        }
        __syncthreads();
    }
#pragma unroll
    for (int i = 0; i < 8; ++i) {
        const int r = bm + ty + ((i < 4) ? i : (60 + i));
        *(float4*)&C[(size_t)r * N + bn + tx]      = make_float4(acc[i][0], acc[i][1], acc[i][2], acc[i][3]);
        *(float4*)&C[(size_t)r * N + bn + tx + 64] = make_float4(acc[i][4], acc[i][5], acc[i][6], acc[i][7]);
    }
}

// ---------------- discoverability bias: d[h][t] = K_h[t]·u_h − mean
__global__ __launch_bounds__(256) void dbias_kernel(const float* __restrict__ K,
                                                    const float* __restrict__ u,
                                                    float* __restrict__ d_bias) {
    const int h = blockIdx.x;
    const int tid = threadIdx.x;
    __shared__ __align__(16) float us[HD];
    __shared__ float dr[T_LEN];
    __shared__ float red[256];
    if (tid < HD) us[tid] = u[h * HD + tid];
    __syncthreads();
    const float4* u4 = (const float4*)us;
    float lsum = 0.f;
    for (int t = tid; t < T_LEN; t += 256) {
        const float4* Kp = (const float4*)&K[(size_t)t * EMB + h * HD];
        float acc = 0.f;
#pragma unroll
        for (int i = 0; i < HD / 4; ++i) {
            float4 k4 = Kp[i];
            float4 uu = u4[i];
            acc += k4.x * uu.x + k4.y * uu.y + k4.z * uu.z + k4.w * uu.w;
        }
        dr[t] = acc;
        lsum += acc;
    }
    red[tid] = lsum;
    __syncthreads();
    for (int off = 128; off > 0; off >>= 1) {
        if (tid < off) red[tid] += red[tid + off];
        __syncthreads();
    }
    const float mean = red[0] * (1.0f / (float)T_LEN);
    __syncthreads();
    for (int t = tid; t < T_LEN; t += 256) {
        d_bias[h * T_LEN + t] = dr[t] - mean;
    }
}

// ---------------- tiled banded attention, flash-style online softmax, fully fused output.
// One block per (64-row t-tile, head). Per chunk: stage K/Q from prefetch regs, fused M1+M2,
// softmax update (p stored to attn with chunk-local max; max recorded in cm[]), P@V.
// Epilogue rescales the band in-place (exp(m_c - m_final)/den, no exp per element) and
// zero-fills outside the band. attn_norm kernel eliminated.
__global__ __launch_bounds__(256) void attn_band_kernel(const float* __restrict__ Q,
                                                        const float* __restrict__ K,
                                                        const float* __restrict__ V,
                                                        const float* __restrict__ d_bias,
                                                        const float* __restrict__ gates,
                                                        float* __restrict__ attn,
                                                        float* __restrict__ ctx) {
    const int t0  = blockIdx.x << 6;
    const int h   = blockIdx.y;
    const int tid = threadIdx.x;
    const int tm  = (tid >> 4) << 2;   // row base within tile (0..60)
    const int tn4 = (tid & 15) << 2;   // col base within chunk (0..60)
    const int lm  = tid >> 2;          // staging: row 0..63
    const int lk  = (tid & 3) << 2;    // staging: k base 0..12

    __shared__ __align__(16) float QT[64][68];  // Q[t0+m][k] -> QT[k][m]
    __shared__ __align__(16) float KT[64][68];  // K[t0+m][k] -> KT[k][m]
    __shared__ __align__(16) float Cc[64][68];  // K chunk transposed / P (time-shared)
    __shared__ __align__(16) float Qs[64][68];  // Q chunk transposed / V row-major (time-shared)
    __shared__ float cm[9][64];                 // per-chunk per-row max -> later scale factor
    __shared__ float rmf[64];                   // final row max
    __shared__ float idvf[64];                  // final 1/den

    // per-head gate softmax (fold 1/sqrt(64) into w_std/w_rec)
    const float g0 = gates[h * 3 + 0];
    const float g1 = gates[h * 3 + 1];
    const float g2 = gates[h * 3 + 2];
    const float gm = fmaxf(g0, fmaxf(g1, g2));
    const float e0 = __expf(g0 - gm), e1 = __expf(g1 - gm), e2 = __expf(g2 - gm);
    const float gi = 1.0f / (e0 + e1 + e2);
    const float w_std = e0 * gi * 0.125f;
    const float w_rec = e1 * gi * 0.125f;
    const float w_disc = e2 * gi;

    // stage this tile's Q and K rows, transposed to [k][m]
    {
        const float* Qp = Q + (size_t)(t0 + lm) * EMB + h * HD + lk;
        const float* Kp = K + (size_t)(t0 + lm) * EMB + h * HD + lk;
#pragma unroll
        for (int it = 0; it < 4; ++it) {
            float4 a = *(const float4*)(Qp + 16 * it);
            QT[lk + 16 * it + 0][lm] = a.x;
            QT[lk + 16 * it + 1][lm] = a.y;
            QT[lk + 16 * it + 2][lm] = a.z;
            QT[lk + 16 * it + 3][lm] = a.w;
            float4 b = *(const float4*)(Kp + 16 * it);
            KT[lk + 16 * it + 0][lm] = b.x;
            KT[lk + 16 * it + 1][lm] = b.y;
            KT[lk + 16 * it + 2][lm] = b.z;
            KT[lk + 16 * it + 3][lm] = b.w;
        }
    }

    const int s_base = (t0 - WIN > 0) ? (t0 - WIN) : 0;
    const int nch = ((t0 + 64) - s_base) >> 6;   // <= 9 chunks

    float rm[4], rden[4], acc[4][4];
#pragma unroll
    for (int i = 0; i < 4; ++i) {
        rm[i] = -1e30f;
        rden[i] = 0.f;
#pragma unroll
        for (int j = 0; j < 4; ++j) acc[i][j] = 0.f;
    }

    // preload chunk 0 into registers
    float4 kr[4], qr[4], vcur[4], vnxt[4];
    {
        const float* Kp = K + (size_t)(s_base + lm) * EMB + h * HD + lk;
        const float* Qp = Q + (size_t)(s_base + lm) * EMB + h * HD + lk;
        const float* Vp = V + (size_t)(s_base + lm) * EMB + h * HD + lk;
#pragma unroll
        for (int it = 0; it < 4; ++it) {
            kr[it]   = *(const float4*)(Kp + 16 * it);
            qr[it]   = *(const float4*)(Qp + 16 * it);
            vcur[it] = *(const float4*)(Vp + 16 * it);
        }
    }

    for (int c = 0; c < nch; ++c) {
        const int s0 = s_base + (c << 6);
        __syncthreads();   // (1) prev chunk's PV reads of Cc/Qs done
        // ds_write K chunk and Q chunk (transposed [k][m]) from prefetch regs
#pragma unroll
        for (int it = 0; it < 4; ++it) {
            Cc[lk + 16 * it + 0][lm] = kr[it].x;
            Cc[lk + 16 * it + 1][lm] = kr[it].y;
            Cc[lk + 16 * it + 2][lm] = kr[it].z;
            Cc[lk + 16 * it + 3][lm] = kr[it].w;
            Qs[lk + 16 * it + 0][lm] = qr[it].x;
            Qs[lk + 16 * it + 1][lm] = qr[it].y;
            Qs[lk + 16 * it + 2][lm] = qr[it].z;
            Qs[lk + 16 * it + 3][lm] = qr[it].w;
        }
        __syncthreads();   // (2)
        // prefetch chunk c+1 (latency hides under M1/M2 compute)
        if (c + 1 < nch) {
            const int s1 = s0 + 64;
            const float* Kp = K + (size_t)(s1 + lm) * EMB + h * HD + lk;
            const float* Qp = Q + (size_t)(s1 + lm) * EMB + h * HD + lk;
            const float* Vp = V + (size_t)(s1 + lm) * EMB + h * HD + lk;
#pragma unroll
            for (int it = 0; it < 4; ++it) {
                kr[it]   = *(const float4*)(Kp + 16 * it);
                qr[it]   = *(const float4*)(Qp + 16 * it);
                vnxt[it] = *(const float4*)(Vp + 16 * it);
            }
        }

        // fused: M1[i][j] = Q[t0+tm+i].K[s0+tn4+j],  M2[i][j] = K[t0+tm+i].Q[s0+tn4+j]
        float m1[4][4] = {};
        float m2[4][4] = {};
#pragma unroll 8
        for (int k = 0; k < 64; ++k) {
            const float4 aq = *(const float4*)&QT[k][tm];
            const float4 bk = *(const float4*)&Cc[k][tn4];
            const float4 ak = *(const float4*)&KT[k][tm];
            const float4 bq = *(const float4*)&Qs[k][tn4];
            m1[0][0] += aq.x * bk.x; m1[0][1] += aq.x * bk.y; m1[0][2] += aq.x * bk.z; m1[0][3] += aq.x * bk.w;
            m1[1][0] += aq.y * bk.x; m1[1][1] += aq.y * bk.y; m1[1][2] += aq.y * bk.z; m1[1][3] += aq.y * bk.w;
            m1[2][0] += aq.z * bk.x; m1[2][1] += aq.z * bk.y; m1[2][2] += aq.z * bk.z; m1[2][3] += aq.z * bk.w;
            m1[3][0] += aq.w * bk.x; m1[3][1] += aq.w * bk.y; m1[3][2] += aq.w * bk.z; m1[3][3] += aq.w * bk.w;
            m2[0][0] += ak.x * bq.x; m2[0][1] += ak.x * bq.y; m2[0][2] += ak.x * bq.z; m2[0][3] += ak.x * bq.w;
            m2[1][0] += ak.y * bq.x; m2[1][1] += ak.y * bq.y; m2[1][2] += ak.y * bq.z; m2[1][3] += ak.y * bq.w;
            m2[2][0] += ak.z * bq.x; m2[2][1] += ak.z * bq.y; m2[2][2] += ak.z * bq.z; m2[2][3] += ak.z * bq.w;
            m2[3][0] += ak.w * bq.x; m2[3][1] += ak.w * bq.y; m2[3][2] += ak.w * bq.z; m2[3][3] += ak.w * bq.w;
        }

        // logits + band mask
        const float4 db = *(const float4*)&d_bias[h * T_LEN + s0 + tn4];
        float l[4][4];
#pragma unroll
        for (int i = 0; i < 4; ++i) {
            const int t = t0 + tm + i;
            const float dbv[4] = {db.x, db.y, db.z, db.w};
#pragma unroll
            for (int j = 0; j < 4; ++j) {
                const int s = s0 + tn4 + j;
                float lv = w_std * m1[i][j] + w_rec * m2[i][j] + w_disc * dbv[j];
                const bool valid = (s <= t) && (s >= t - WIN);
                l[i][j] = valid ? lv : -1e30f;
            }
        }
        // chunk row max across the 16 lanes owning each row
        float cmx[4];
#pragma unroll
        for (int i = 0; i < 4; ++i)
            cmx[i] = fmaxf(fmaxf(l[i][0], l[i][1]), fmaxf(l[i][2], l[i][3]));
#pragma unroll
        for (int off = 1; off < 16; off <<= 1) {
#pragma unroll
            for (int i = 0; i < 4; ++i) cmx[i] = fmaxf(cmx[i], __shfl_xor(cmx[i], off));
        }
        // online update: rescale den/ctx, l -> p; store p (chunk-local scaling) + chunk max
        float cs[4];
#pragma unroll
        for (int i = 0; i < 4; ++i) {
            const float nm = fmaxf(rm[i], cmx[i]);
            const float f = __expf(rm[i] - nm);
            float s = 0.f;
#pragma unroll
            for (int j = 0; j < 4; ++j) {
                const float p = __expf(l[i][j] - nm);
                l[i][j] = p;
                s += p;
            }
            cs[i] = s;
            rm[i] = nm;
            rden[i] *= f;
#pragma unroll
            for (int j = 0; j < 4; ++j) acc[i][j] *= f;
            *(float4*)&attn[((size_t)(h * T_LEN + t0 + tm + i)) * T_LEN + s0 + tn4] =
                make_float4(l[i][0], l[i][1], l[i][2], l[i][3]);
            if ((tid & 15) == 0) cm[c][tm + i] = nm;
        }
#pragma unroll
        for (int off = 1; off < 16; off <<= 1) {
#pragma unroll
            for (int i = 0; i < 4; ++i) cs[i] += __shfl_xor(cs[i], off);
        }
#pragma unroll
        for (int i = 0; i < 4; ++i) rden[i] += cs[i];

        __syncthreads();   // (3) all M1/M2 reads of Cc/Qs done
        // scatter P into Cc as [k][m]; ds_write V chunk (row-major) into Qs
#pragma unroll
        for (int i = 0; i < 4; ++i)
#pragma unroll
            for (int j = 0; j < 4; ++j)
                Cc[tn4 + j][tm + i] = l[i][j];
#pragma unroll
        for (int it = 0; it < 4; ++it)
            *(float4*)&Qs[lm][lk + 16 * it] = vcur[it];
        __syncthreads();   // (4)

        // ctx += P @ V
#pragma unroll 16
        for (int k = 0; k < 64; ++k) {
            const float4 av = *(const float4*)&Cc[k][tm];
            const float4 bv = *(const float4*)&Qs[k][tn4];
            acc[0][0] += av.x * bv.x; acc[0][1] += av.x * bv.y; acc[0][2] += av.x * bv.z; acc[0][3] += av.x * bv.w;
            acc[1][0] += av.y * bv.x; acc[1][1] += av.y * bv.y; acc[1][2] += av.y * bv.z; acc[1][3] += av.y * bv.w;
            acc[2][0] += av.z * bv.x; acc[2][1] += av.z * bv.y; acc[2][2] += av.z * bv.z; acc[2][3] += av.z * bv.w;
            acc[3][0] += av.w * bv.x; acc[3][1] += av.w * bv.y; acc[3][2] += av.w * bv.z; acc[3][3] += av.w * bv.w;
        }
#pragma unroll
        for (int it = 0; it < 4; ++it) vcur[it] = vnxt[it];
    }

    // ---- epilogue: ctx, then in-place band rescale + zero-fill (replaces attn_norm) ----
    float idv[4];
#pragma unroll
    for (int i = 0; i < 4; ++i) {
        idv[i] = 1.0f / rden[i];
        *(float4*)&ctx[(size_t)(t0 + tm + i) * EMB + h * HD + tn4] =
            make_float4(acc[i][0] * idv[i], acc[i][1] * idv[i], acc[i][2] * idv[i], acc[i][3] * idv[i]);
    }
    if ((tid & 15) == 0) {
#pragma unroll
        for (int i = 0; i < 4; ++i) {
            rmf[tm + i] = rm[i];
            idvf[tm + i] = idv[i];
        }
    }
    __syncthreads();
    // cm[c][r] -> scale factor exp(m_c - m_final) / den  (576 values, one exp each)
    for (int idx = tid; idx < (nch << 6); idx += 256) {
        const int c = idx >> 6, r = idx & 63;
        cm[c][r] = __expf(cm[c][r] - rmf[r]) * idvf[r];
    }
    __syncthreads();
    // rescale own band positions in place (same-thread global RMW, L2-hot)
    for (int c = 0; c < nch; ++c) {
        const int s0 = s_base + (c << 6);
#pragma unroll
        for (int i = 0; i < 4; ++i) {
            float* p = &attn[((size_t)(h * T_LEN + t0 + tm + i)) * T_LEN + s0 + tn4];
            const float f = cm[c][tm + i];
            const float4 v = *(const float4*)p;
            *(float4*)p = make_float4(v.x * f, v.y * f, v.z * f, v.w * f);
        }
    }
    // zero-fill outside [s_base, t0+64): pure streaming writes
    const int s_end = s_base + (nch << 6);   // == t0 + 64
    const int wv = tid >> 6, ln = tid & 63;
    const float4 z4 = make_float4(0.f, 0.f, 0.f, 0.f);
    for (int r = wv; r < 64; r += 4) {
        float* arow = attn + ((size_t)(h * T_LEN + t0 + r)) * T_LEN;
        for (int col = ln << 2; col < s_base; col += 256)
            *(float4*)&arow[col] = z4;
        for (int col = s_end + (ln << 2); col < T_LEN; col += 256)
            *(float4*)&arow[col] = z4;
    }
}

extern "C" void kernel_launch(void* const* d_in, const int* in_sizes, int n_in,
                              void* d_out, int out_size, void* d_ws, size_t ws_size,
                              hipStream_t stream) {
    const float* x     = (const float*)d_in[0];
    const float* Wq    = (const float*)d_in[1];
    const float* Wk    = (const float*)d_in[2];
    const float* Wv    = (const float*)d_in[3];
    const float* Wo    = (const float*)d_in[4];
    const float* gates = (const float*)d_in[5];
    const float* u     = (const float*)d_in[6];

    float* out  = (float*)d_out;                       // [T, E]
    float* attn = out + (size_t)T_LEN * EMB;           // [H, T, T]

    float* ws = (float*)d_ws;
    float* Qb = ws;
    float* Kb = Qb + (size_t)T_LEN * EMB;
    float* Vb = Kb + (size_t)T_LEN * EMB;
    float* Cb = Vb + (size_t)T_LEN * EMB;
    float* Db = Cb + (size_t)T_LEN * EMB;              // d bias [H, T]

    // fused QKV projection: blockIdx.z selects (Wq->Qb, Wk->Kb, Wv->Vb)
    gemm3_f32<<<dim3(EMB / GBN, T_LEN / GBM, 3), 256, 0, stream>>>(
        x, Wq, Wk, Wv, Qb, Kb, Vb, T_LEN, EMB, EMB);
    dbias_kernel<<<NH, 256, 0, stream>>>(Kb, u, Db);

    // banded attention with fused normalization + zero-fill
    attn_band_kernel<<<dim3(T_LEN / 64, NH), 256, 0, stream>>>(Qb, Kb, Vb, Db, gates,
                                                               attn, Cb);

    // output projection
    gemm3_f32<<<dim3(EMB / GBN, T_LEN / GBM, 1), 256, 0, stream>>>(
        Cb, Wo, Wo, Wo, out, out, out, T_LEN, EMB, EMB);
}

// Round 5
// 1495.660 us; speedup vs baseline: 1.0023x; 1.0023x over previous
//
#include <hip/hip_runtime.h>
#include <cstddef>

#define T_LEN 4096
#define EMB 768
#define NH 12
#define HD 64
#define WIN 512

// ---------------- GEMM f32, 128x128 tile, 8x8 microtile, up to 3 B/C pairs via blockIdx.z.
#define GBM 128
#define GBN 128
#define GBK 16

__global__ __launch_bounds__(256) void gemm3_f32(const float* __restrict__ A,
                                                 const float* __restrict__ B0,
                                                 const float* __restrict__ B1,
                                                 const float* __restrict__ B2,
                                                 float* __restrict__ C0,
                                                 float* __restrict__ C1,
                                                 float* __restrict__ C2,
                                                 int M, int N, int K) {
    __shared__ float As[GBK][GBM + 4];   // A transposed: [k][m]
    __shared__ float Bs[GBK][GBN + 4];   // B row-major:  [k][n]
    const int tid = threadIdx.x;
    const int bm = blockIdx.y * GBM;
    const int bn = blockIdx.x * GBN;
    const float* __restrict__ B = (blockIdx.z == 0) ? B0 : (blockIdx.z == 1) ? B1 : B2;
    float* __restrict__ C = (blockIdx.z == 0) ? C0 : (blockIdx.z == 1) ? C1 : C2;

    const int ty = (tid >> 4) << 2;
    const int tx = (tid & 15) << 2;

    const int ar = tid >> 1;
    const int ac = (tid & 1) << 3;
    const int br = tid >> 4;
    const int bc = (tid & 15) << 3;

    float acc[8][8] = {};

    float4 pa0 = *(const float4*)&A[(size_t)(bm + ar) * K + ac];
    float4 pa1 = *(const float4*)&A[(size_t)(bm + ar) * K + ac + 4];
    float4 pb0 = *(const float4*)&B[(size_t)br * N + bn + bc];
    float4 pb1 = *(const float4*)&B[(size_t)br * N + bn + bc + 4];

    for (int k0 = 0; k0 < K; k0 += GBK) {
        As[ac + 0][ar] = pa0.x; As[ac + 1][ar] = pa0.y; As[ac + 2][ar] = pa0.z; As[ac + 3][ar] = pa0.w;
        As[ac + 4][ar] = pa1.x; As[ac + 5][ar] = pa1.y; As[ac + 6][ar] = pa1.z; As[ac + 7][ar] = pa1.w;
        *(float4*)&Bs[br][bc]     = pb0;
        *(float4*)&Bs[br][bc + 4] = pb1;
        __syncthreads();
        if (k0 + GBK < K) {
            pa0 = *(const float4*)&A[(size_t)(bm + ar) * K + k0 + GBK + ac];
            pa1 = *(const float4*)&A[(size_t)(bm + ar) * K + k0 + GBK + ac + 4];
            pb0 = *(const float4*)&B[(size_t)(k0 + GBK + br) * N + bn + bc];
            pb1 = *(const float4*)&B[(size_t)(k0 + GBK + br) * N + bn + bc + 4];
        }
#pragma unroll
        for (int k = 0; k < GBK; ++k) {
            const float4 a0v = *(const float4*)&As[k][ty];
            const float4 a1v = *(const float4*)&As[k][ty + 64];
            const float4 b0v = *(const float4*)&Bs[k][tx];
            const float4 b1v = *(const float4*)&Bs[k][tx + 64];
            const float av[8] = {a0v.x, a0v.y, a0v.z, a0v.w, a1v.x, a1v.y, a1v.z, a1v.w};
            const float bv[8] = {b0v.x, b0v.y, b0v.z, b0v.w, b1v.x, b1v.y, b1v.z, b1v.w};
#pragma unroll
            for (int i = 0; i < 8; ++i)
#pragma unroll
                for (int j = 0; j < 8; ++j)
                    acc[i][j] += av[i] * bv[j];
        }
        __syncthreads();
    }
#pragma unroll
    for (int i = 0; i < 8; ++i) {
        const int r = bm + ty + ((i < 4) ? i : (60 + i));
        *(float4*)&C[(size_t)r * N + bn + tx]      = make_float4(acc[i][0], acc[i][1], acc[i][2], acc[i][3]);
        *(float4*)&C[(size_t)r * N + bn + tx + 64] = make_float4(acc[i][4], acc[i][5], acc[i][6], acc[i][7]);
    }
}

// ---------------- discoverability bias: d[h][t] = K_h[t]·u_h − mean
__global__ __launch_bounds__(256) void dbias_kernel(const float* __restrict__ K,
                                                    const float* __restrict__ u,
                                                    float* __restrict__ d_bias) {
    const int h = blockIdx.x;
    const int tid = threadIdx.x;
    __shared__ __align__(16) float us[HD];
    __shared__ float dr[T_LEN];
    __shared__ float red[256];
    if (tid < HD) us[tid] = u[h * HD + tid];
    __syncthreads();
    const float4* u4 = (const float4*)us;
    float lsum = 0.f;
    for (int t = tid; t < T_LEN; t += 256) {
        const float4* Kp = (const float4*)&K[(size_t)t * EMB + h * HD];
        float acc = 0.f;
#pragma unroll
        for (int i = 0; i < HD / 4; ++i) {
            float4 k4 = Kp[i];
            float4 uu = u4[i];
            acc += k4.x * uu.x + k4.y * uu.y + k4.z * uu.z + k4.w * uu.w;
        }
        dr[t] = acc;
        lsum += acc;
    }
    red[tid] = lsum;
    __syncthreads();
    for (int off = 128; off > 0; off >>= 1) {
        if (tid < off) red[tid] += red[tid + off];
        __syncthreads();
    }
    const float mean = red[0] * (1.0f / (float)T_LEN);
    __syncthreads();
    for (int t = tid; t < T_LEN; t += 256) {
        d_bias[h * T_LEN + t] = dr[t] - mean;
    }
}

// ---------------- banded attention, pair-chunks (128 cols), flash softmax, fused epilogue.
// Block = (64 t-rows, head). 256 threads = 16 row-groups x 16 col-groups.
// M1/M2: 4x8 split-fragment microtile (cols tn4 and tn4+64) over 128-wide chunk pairs.
// V read directly from global in PV (L1/L2-hot); P^T scattered into the chunk buffer as b128.
__global__ __launch_bounds__(256) void attn_band_kernel(const float* __restrict__ Q,
                                                        const float* __restrict__ K,
                                                        const float* __restrict__ V,
                                                        const float* __restrict__ d_bias,
                                                        const float* __restrict__ gates,
                                                        float* __restrict__ attn,
                                                        float* __restrict__ ctx) {
    const int t0  = blockIdx.x << 6;
    const int h   = blockIdx.y;
    const int tid = threadIdx.x;
    const int cg  = tid & 15;          // col group 0..15
    const int tm  = (tid >> 4) << 2;   // row base 0..60
    const int tn4 = cg << 2;           // col base within each 64-half

    const int lm = tid >> 2;           // tile staging: row 0..63
    const int lk = (tid & 3) << 4;     // tile staging: col base {0,16,32,48}
    const int sr = tid >> 1;           // pair staging: row 0..127
    const int sc = (tid & 1) << 5;     // pair staging: col base {0,32}

    __shared__ __align__(16) float QT[64][68];   // Q tile transposed [k][m]
    __shared__ __align__(16) float KT[64][68];   // K tile transposed [k][m]
    __shared__ __align__(16) float Bc[64][136];  // K-pair / Q-pair transposed [k][s_loc]; aliased as PT[128][68]
    __shared__ float cmf[5][64];                 // per-pair per-row running max -> scale factor
    __shared__ float rmf[64], idvf[64];
    float* __restrict__ Bp = &Bc[0][0];

    // per-head gate softmax (fold 1/sqrt(64) into w_std/w_rec)
    const float g0 = gates[h * 3 + 0];
    const float g1 = gates[h * 3 + 1];
    const float g2 = gates[h * 3 + 2];
    const float gm = fmaxf(g0, fmaxf(g1, g2));
    const float e0 = __expf(g0 - gm), e1 = __expf(g1 - gm), e2 = __expf(g2 - gm);
    const float gi = 1.0f / (e0 + e1 + e2);
    const float w_std = e0 * gi * 0.125f;
    const float w_rec = e1 * gi * 0.125f;
    const float w_disc = e2 * gi;

    const int cp_start = (t0 >= 576) ? 0 : ((576 - t0) >> 7);
    int s0 = t0 - 576 + (cp_start << 7);       // >= -64, multiple of 64

    // prefetch first K-pair
    float4 kr[8], qr[8];
    {
        int srow = s0 + sr; srow = srow < 0 ? 0 : srow;
        const float* Kp = K + (size_t)srow * EMB + h * HD + sc;
#pragma unroll
        for (int c = 0; c < 8; ++c) kr[c] = *(const float4*)(Kp + 4 * c);
    }

    // stage t-tile Q and K, transposed [k][m]
    {
        const float* Qp = Q + (size_t)(t0 + lm) * EMB + h * HD + lk;
        const float* Kp = K + (size_t)(t0 + lm) * EMB + h * HD + lk;
#pragma unroll
        for (int it = 0; it < 4; ++it) {
            float4 a = *(const float4*)(Qp + 4 * it);
            QT[lk + 4 * it + 0][lm] = a.x;
            QT[lk + 4 * it + 1][lm] = a.y;
            QT[lk + 4 * it + 2][lm] = a.z;
            QT[lk + 4 * it + 3][lm] = a.w;
            float4 b = *(const float4*)(Kp + 4 * it);
            KT[lk + 4 * it + 0][lm] = b.x;
            KT[lk + 4 * it + 1][lm] = b.y;
            KT[lk + 4 * it + 2][lm] = b.z;
            KT[lk + 4 * it + 3][lm] = b.w;
        }
    }

    float rm[4], rden[4], acc[4][4];
#pragma unroll
    for (int i = 0; i < 4; ++i) {
        rm[i] = -1e30f;
        rden[i] = 0.f;
#pragma unroll
        for (int j = 0; j < 4; ++j) acc[i][j] = 0.f;
    }

    for (int cp = cp_start; cp < 5; ++cp) {
        __syncthreads();   // b1: prev PV reads of Bp done (and tile staging visible on first iter)
        // write K-pair transposed [k][s_loc]
#pragma unroll
        for (int c = 0; c < 8; ++c) {
            Bc[sc + 4 * c + 0][sr] = kr[c].x;
            Bc[sc + 4 * c + 1][sr] = kr[c].y;
            Bc[sc + 4 * c + 2][sr] = kr[c].z;
            Bc[sc + 4 * c + 3][sr] = kr[c].w;
        }
        __syncthreads();   // b2

        // issue Q-pair loads (current pair); latency hides under M1
        {
            int srow = s0 + sr; srow = srow < 0 ? 0 : srow;
            const float* Qp = Q + (size_t)srow * EMB + h * HD + sc;
#pragma unroll
            for (int c = 0; c < 8; ++c) qr[c] = *(const float4*)(Qp + 4 * c);
        }

        // M1[i][j] = Q[t0+tm+i] . K[s0 + col(j)]
        float m1[4][8] = {};
#pragma unroll 8
        for (int k = 0; k < 64; ++k) {
            const float4 a4 = *(const float4*)&QT[k][tm];
            const float4 b0 = *(const float4*)&Bc[k][tn4];
            const float4 b1 = *(const float4*)&Bc[k][tn4 + 64];
            const float av[4] = {a4.x, a4.y, a4.z, a4.w};
            const float bv[8] = {b0.x, b0.y, b0.z, b0.w, b1.x, b1.y, b1.z, b1.w};
#pragma unroll
            for (int i = 0; i < 4; ++i)
#pragma unroll
                for (int j = 0; j < 8; ++j)
                    m1[i][j] += av[i] * bv[j];
        }
        __syncthreads();   // b3: M1 reads of Bc done

        // write Q-pair transposed
#pragma unroll
        for (int c = 0; c < 8; ++c) {
            Bc[sc + 4 * c + 0][sr] = qr[c].x;
            Bc[sc + 4 * c + 1][sr] = qr[c].y;
            Bc[sc + 4 * c + 2][sr] = qr[c].z;
            Bc[sc + 4 * c + 3][sr] = qr[c].w;
        }
        __syncthreads();   // b4

        // issue next K-pair loads; latency hides under M2+PV
        if (cp < 4) {
            int srow = s0 + 128 + sr; srow = srow < 0 ? 0 : srow;
            const float* Kp = K + (size_t)srow * EMB + h * HD + sc;
#pragma unroll
            for (int c = 0; c < 8; ++c) kr[c] = *(const float4*)(Kp + 4 * c);
        }

        // M2[i][j] = K[t0+tm+i] . Q[s0 + col(j)]
        float m2[4][8] = {};
#pragma unroll 8
        for (int k = 0; k < 64; ++k) {
            const float4 a4 = *(const float4*)&KT[k][tm];
            const float4 b0 = *(const float4*)&Bc[k][tn4];
            const float4 b1 = *(const float4*)&Bc[k][tn4 + 64];
            const float av[4] = {a4.x, a4.y, a4.z, a4.w};
            const float bv[8] = {b0.x, b0.y, b0.z, b0.w, b1.x, b1.y, b1.z, b1.w};
#pragma unroll
            for (int i = 0; i < 4; ++i)
#pragma unroll
                for (int j = 0; j < 8; ++j)
                    m2[i][j] += av[i] * bv[j];
        }

        // logits + masks (note: s can be < 0 for the left-edge pair)
        const int i0 = s0 + tn4;
        const int i0c = i0 < 0 ? 0 : i0;
        const float4 db0 = *(const float4*)&d_bias[h * T_LEN + i0c];
        const float4 db1 = *(const float4*)&d_bias[h * T_LEN + s0 + 64 + tn4];
        const float dbv[8] = {db0.x, db0.y, db0.z, db0.w, db1.x, db1.y, db1.z, db1.w};
        float l[4][8];
#pragma unroll
        for (int i = 0; i < 4; ++i) {
            const int t = t0 + tm + i;
#pragma unroll
            for (int j = 0; j < 8; ++j) {
                const int s = s0 + ((j < 4) ? (tn4 + j) : (tn4 + j + 60));
                const float lv = w_std * m1[i][j] + w_rec * m2[i][j] + w_disc * dbv[j];
                const bool valid = (s >= 0) && (s <= t) && (s >= t - WIN);
                l[i][j] = valid ? lv : -1e30f;
            }
        }
        // online softmax: row max across 8 own cols + 16 col-groups
#pragma unroll
        for (int i = 0; i < 4; ++i) {
            float cmx = fmaxf(fmaxf(fmaxf(l[i][0], l[i][1]), fmaxf(l[i][2], l[i][3])),
                              fmaxf(fmaxf(l[i][4], l[i][5]), fmaxf(l[i][6], l[i][7])));
#pragma unroll
            for (int off = 1; off < 16; off <<= 1) cmx = fmaxf(cmx, __shfl_xor(cmx, off));
            const float nm = fmaxf(rm[i], cmx);
            const float f = __expf(rm[i] - nm);
            float cs = 0.f;
#pragma unroll
            for (int j = 0; j < 8; ++j) {
                const float p = __expf(l[i][j] - nm);
                l[i][j] = p;
                cs += p;
            }
#pragma unroll
            for (int off = 1; off < 16; off <<= 1) cs += __shfl_xor(cs, off);
            rden[i] = rden[i] * f + cs;
            rm[i] = nm;
#pragma unroll
            for (int j = 0; j < 4; ++j) acc[i][j] *= f;
            if (cg == 0) cmf[cp][tm + i] = nm;
            // store p (pair-local max scaling); guard left half when below 0
            float* arow = &attn[((size_t)(h * T_LEN + t0 + tm + i)) * T_LEN];
            if (s0 >= 0)
                *(float4*)&arow[s0 + tn4] = make_float4(l[i][0], l[i][1], l[i][2], l[i][3]);
            *(float4*)&arow[s0 + 64 + tn4] = make_float4(l[i][4], l[i][5], l[i][6], l[i][7]);
        }
        __syncthreads();   // b5: M2 reads of Bc done

        // scatter P^T into Bp[k][m] as float4 (k = s-local col)
#pragma unroll
        for (int j = 0; j < 4; ++j) {
            *(float4*)&Bp[(tn4 + j) * 68 + tm] =
                make_float4(l[0][j], l[1][j], l[2][j], l[3][j]);
            *(float4*)&Bp[(tn4 + j + 64) * 68 + tm] =
                make_float4(l[0][j + 4], l[1][j + 4], l[2][j + 4], l[3][j + 4]);
        }
        __syncthreads();   // b6

        // ctx += P @ V, V straight from global (L1/L2-hot chunk)
#pragma unroll 8
        for (int k = 0; k < 128; ++k) {
            const float4 av = *(const float4*)&Bp[k * 68 + tm];
            int vrow = s0 + k; vrow = vrow < 0 ? 0 : vrow;
            const float4 bv = *(const float4*)&V[(size_t)vrow * EMB + h * HD + tn4];
            acc[0][0] += av.x * bv.x; acc[0][1] += av.x * bv.y; acc[0][2] += av.x * bv.z; acc[0][3] += av.x * bv.w;
            acc[1][0] += av.y * bv.x; acc[1][1] += av.y * bv.y; acc[1][2] += av.y * bv.z; acc[1][3] += av.y * bv.w;
            acc[2][0] += av.z * bv.x; acc[2][1] += av.z * bv.y; acc[2][2] += av.z * bv.z; acc[2][3] += av.z * bv.w;
            acc[3][0] += av.w * bv.x; acc[3][1] += av.w * bv.y; acc[3][2] += av.w * bv.z; acc[3][3] += av.w * bv.w;
        }
        s0 += 128;
    }

    // ---- epilogue: ctx, band rescale in place, zero-fill outside band ----
    float idv[4];
#pragma unroll
    for (int i = 0; i < 4; ++i) {
        idv[i] = 1.0f / rden[i];
        *(float4*)&ctx[(size_t)(t0 + tm + i) * EMB + h * HD + tn4] =
            make_float4(acc[i][0] * idv[i], acc[i][1] * idv[i], acc[i][2] * idv[i], acc[i][3] * idv[i]);
    }
    if (cg == 0) {
#pragma unroll
        for (int i = 0; i < 4; ++i) {
            rmf[tm + i] = rm[i];
            idvf[tm + i] = idv[i];
        }
    }
    __syncthreads();
    for (int idx = tid; idx < 320; idx += 256) {
        const int c = idx >> 6, r = idx & 63;
        if (c >= cp_start) cmf[c][r] = __expf(cmf[c][r] - rmf[r]) * idvf[r];
    }
    __syncthreads();
    // rescale own stored positions (same thread wrote them)
    int ss = t0 - 576 + (cp_start << 7);
    for (int cp = cp_start; cp < 5; ++cp, ss += 128) {
#pragma unroll
        for (int half = 0; half < 2; ++half) {
            const int cbase = ss + (half << 6);
            if (cbase >= 0) {
#pragma unroll
                for (int i = 0; i < 4; ++i) {
                    const float f = cmf[cp][tm + i];
                    float* p = &attn[((size_t)(h * T_LEN + t0 + tm + i)) * T_LEN + cbase + tn4];
                    const float4 v = *(const float4*)p;
                    *(float4*)p = make_float4(v.x * f, v.y * f, v.z * f, v.w * f);
                }
            }
        }
    }
    // zero-fill [0, stored_left) and [t0+64, T)
    const int sl = t0 - 576 + (cp_start << 7);
    const int stored_left = sl < 0 ? 0 : sl;
    const int wv = tid >> 6, ln = tid & 63;
    const float4 z4 = make_float4(0.f, 0.f, 0.f, 0.f);
    for (int r = wv; r < 64; r += 4) {
        float* arow = attn + ((size_t)(h * T_LEN + t0 + r)) * T_LEN;
        for (int col = ln << 2; col < stored_left; col += 256)
            *(float4*)&arow[col] = z4;
        for (int col = t0 + 64 + (ln << 2); col < T_LEN; col += 256)
            *(float4*)&arow[col] = z4;
    }
}

extern "C" void kernel_launch(void* const* d_in, const int* in_sizes, int n_in,
                              void* d_out, int out_size, void* d_ws, size_t ws_size,
                              hipStream_t stream) {
    const float* x     = (const float*)d_in[0];
    const float* Wq    = (const float*)d_in[1];
    const float* Wk    = (const float*)d_in[2];
    const float* Wv    = (const float*)d_in[3];
    const float* Wo    = (const float*)d_in[4];
    const float* gates = (const float*)d_in[5];
    const float* u     = (const float*)d_in[6];

    float* out  = (float*)d_out;                       // [T, E]
    float* attn = out + (size_t)T_LEN * EMB;           // [H, T, T]

    float* ws = (float*)d_ws;
    float* Qb = ws;
    float* Kb = Qb + (size_t)T_LEN * EMB;
    float* Vb = Kb + (size_t)T_LEN * EMB;
    float* Cb = Vb + (size_t)T_LEN * EMB;
    float* Db = Cb + (size_t)T_LEN * EMB;              // d bias [H, T]

    gemm3_f32<<<dim3(EMB / GBN, T_LEN / GBM, 3), 256, 0, stream>>>(
        x, Wq, Wk, Wv, Qb, Kb, Vb, T_LEN, EMB, EMB);
    dbias_kernel<<<NH, 256, 0, stream>>>(Kb, u, Db);

    attn_band_kernel<<<dim3(T_LEN / 64, NH), 256, 0, stream>>>(Qb, Kb, Vb, Db, gates,
                                                               attn, Cb);

    gemm3_f32<<<dim3(EMB / GBN, T_LEN / GBM, 1), 256, 0, stream>>>(
        Cb, Wo, Wo, Wo, out, out, out, T_LEN, EMB, EMB);
}

// Round 6
// 1447.617 us; speedup vs baseline: 1.0356x; 1.0332x over previous
//
#include <hip/hip_runtime.h>
#include <cstddef>

#define T_LEN 4096
#define EMB 768
#define NH 12
#define HD 64
#define WIN 512
#define PBW 640   // compact band width per row (5 pairs x 128)

// ---------------- GEMM f32, 128x128 tile, 8x8 microtile, up to 3 B/C pairs via blockIdx.z.
#define GBM 128
#define GBN 128
#define GBK 16

__global__ __launch_bounds__(256) void gemm3_f32(const float* __restrict__ A,
                                                 const float* __restrict__ B0,
                                                 const float* __restrict__ B1,
                                                 const float* __restrict__ B2,
                                                 float* __restrict__ C0,
                                                 float* __restrict__ C1,
                                                 float* __restrict__ C2,
                                                 int M, int N, int K) {
    __shared__ float As[GBK][GBM + 4];   // A transposed: [k][m]
    __shared__ float Bs[GBK][GBN + 4];   // B row-major:  [k][n]
    const int tid = threadIdx.x;
    const int bm = blockIdx.y * GBM;
    const int bn = blockIdx.x * GBN;
    const float* __restrict__ B = (blockIdx.z == 0) ? B0 : (blockIdx.z == 1) ? B1 : B2;
    float* __restrict__ C = (blockIdx.z == 0) ? C0 : (blockIdx.z == 1) ? C1 : C2;

    const int ty = (tid >> 4) << 2;
    const int tx = (tid & 15) << 2;

    const int ar = tid >> 1;
    const int ac = (tid & 1) << 3;
    const int br = tid >> 4;
    const int bc = (tid & 15) << 3;

    float acc[8][8] = {};

    float4 pa0 = *(const float4*)&A[(size_t)(bm + ar) * K + ac];
    float4 pa1 = *(const float4*)&A[(size_t)(bm + ar) * K + ac + 4];
    float4 pb0 = *(const float4*)&B[(size_t)br * N + bn + bc];
    float4 pb1 = *(const float4*)&B[(size_t)br * N + bn + bc + 4];

    for (int k0 = 0; k0 < K; k0 += GBK) {
        As[ac + 0][ar] = pa0.x; As[ac + 1][ar] = pa0.y; As[ac + 2][ar] = pa0.z; As[ac + 3][ar] = pa0.w;
        As[ac + 4][ar] = pa1.x; As[ac + 5][ar] = pa1.y; As[ac + 6][ar] = pa1.z; As[ac + 7][ar] = pa1.w;
        *(float4*)&Bs[br][bc]     = pb0;
        *(float4*)&Bs[br][bc + 4] = pb1;
        __syncthreads();
        if (k0 + GBK < K) {
            pa0 = *(const float4*)&A[(size_t)(bm + ar) * K + k0 + GBK + ac];
            pa1 = *(const float4*)&A[(size_t)(bm + ar) * K + k0 + GBK + ac + 4];
            pb0 = *(const float4*)&B[(size_t)(k0 + GBK + br) * N + bn + bc];
            pb1 = *(const float4*)&B[(size_t)(k0 + GBK + br) * N + bn + bc + 4];
        }
#pragma unroll
        for (int k = 0; k < GBK; ++k) {
            const float4 a0v = *(const float4*)&As[k][ty];
            const float4 a1v = *(const float4*)&As[k][ty + 64];
            const float4 b0v = *(const float4*)&Bs[k][tx];
            const float4 b1v = *(const float4*)&Bs[k][tx + 64];
            const float av[8] = {a0v.x, a0v.y, a0v.z, a0v.w, a1v.x, a1v.y, a1v.z, a1v.w};
            const float bv[8] = {b0v.x, b0v.y, b0v.z, b0v.w, b1v.x, b1v.y, b1v.z, b1v.w};
#pragma unroll
            for (int i = 0; i < 8; ++i)
#pragma unroll
                for (int j = 0; j < 8; ++j)
                    acc[i][j] += av[i] * bv[j];
        }
        __syncthreads();
    }
#pragma unroll
    for (int i = 0; i < 8; ++i) {
        const int r = bm + ty + ((i < 4) ? i : (60 + i));
        *(float4*)&C[(size_t)r * N + bn + tx]      = make_float4(acc[i][0], acc[i][1], acc[i][2], acc[i][3]);
        *(float4*)&C[(size_t)r * N + bn + tx + 64] = make_float4(acc[i][4], acc[i][5], acc[i][6], acc[i][7]);
    }
}

// ---------------- discoverability bias: d[h][t] = K_h[t]·u_h − mean
__global__ __launch_bounds__(256) void dbias_kernel(const float* __restrict__ K,
                                                    const float* __restrict__ u,
                                                    float* __restrict__ d_bias) {
    const int h = blockIdx.x;
    const int tid = threadIdx.x;
    __shared__ __align__(16) float us[HD];
    __shared__ float dr[T_LEN];
    __shared__ float red[256];
    if (tid < HD) us[tid] = u[h * HD + tid];
    __syncthreads();
    const float4* u4 = (const float4*)us;
    float lsum = 0.f;
    for (int t = tid; t < T_LEN; t += 256) {
        const float4* Kp = (const float4*)&K[(size_t)t * EMB + h * HD];
        float acc = 0.f;
#pragma unroll
        for (int i = 0; i < HD / 4; ++i) {
            float4 k4 = Kp[i];
            float4 uu = u4[i];
            acc += k4.x * uu.x + k4.y * uu.y + k4.z * uu.z + k4.w * uu.w;
        }
        dr[t] = acc;
        lsum += acc;
    }
    red[tid] = lsum;
    __syncthreads();
    for (int off = 128; off > 0; off >>= 1) {
        if (tid < off) red[tid] += red[tid + off];
        __syncthreads();
    }
    const float mean = red[0] * (1.0f / (float)T_LEN);
    __syncthreads();
    for (int t = tid; t < T_LEN; t += 256) {
        d_bias[h * T_LEN + t] = dr[t] - mean;
    }
}

// ---------------- banded attention, pair-chunks (128 cols), flash softmax.
// Stores p COMPACTLY (pair-local max scaling) into Pb[h][t][640]; per-pair rescale
// factors exp(m_pair - m_final)/den into Fb[h][t][5]. No full-row output here —
// attn_expand_kernel streams the final [H,T,T] matrix.
__global__ __launch_bounds__(256) void attn_band_kernel(const float* __restrict__ Q,
                                                        const float* __restrict__ K,
                                                        const float* __restrict__ V,
                                                        const float* __restrict__ d_bias,
                                                        const float* __restrict__ gates,
                                                        float* __restrict__ Pb,
                                                        float* __restrict__ Fb,
                                                        float* __restrict__ ctx) {
    const int t0  = blockIdx.x << 6;
    const int h   = blockIdx.y;
    const int tid = threadIdx.x;
    const int cg  = tid & 15;          // col group 0..15
    const int tm  = (tid >> 4) << 2;   // row base 0..60
    const int tn4 = cg << 2;           // col base within each 64-half

    const int lm = tid >> 2;           // tile staging: row 0..63
    const int lk = (tid & 3) << 4;     // tile staging: col base {0,16,32,48}
    const int sr = tid >> 1;           // pair staging: row 0..127
    const int sc = (tid & 1) << 5;     // pair staging: col base {0,32}

    __shared__ __align__(16) float QT[64][68];   // Q tile transposed [k][m]
    __shared__ __align__(16) float KT[64][68];   // K tile transposed [k][m]
    __shared__ __align__(16) float Bc[64][136];  // K-pair / Q-pair transposed [k][s_loc]; aliased as PT[128][68]
    __shared__ float cmf[5][64];                 // per-pair per-row running max
    __shared__ float rmf[64], idvf[64];
    float* __restrict__ Bp = &Bc[0][0];

    // per-head gate softmax (fold 1/sqrt(64) into w_std/w_rec)
    const float g0 = gates[h * 3 + 0];
    const float g1 = gates[h * 3 + 1];
    const float g2 = gates[h * 3 + 2];
    const float gm = fmaxf(g0, fmaxf(g1, g2));
    const float e0 = __expf(g0 - gm), e1 = __expf(g1 - gm), e2 = __expf(g2 - gm);
    const float gi = 1.0f / (e0 + e1 + e2);
    const float w_std = e0 * gi * 0.125f;
    const float w_rec = e1 * gi * 0.125f;
    const float w_disc = e2 * gi;

    const int cp_start = (t0 >= 576) ? 0 : ((576 - t0) >> 7);
    int s0 = t0 - 576 + (cp_start << 7);       // >= -64, multiple of 64

    // prefetch first K-pair
    float4 kr[8], qr[8];
    {
        int srow = s0 + sr; srow = srow < 0 ? 0 : srow;
        const float* Kp = K + (size_t)srow * EMB + h * HD + sc;
#pragma unroll
        for (int c = 0; c < 8; ++c) kr[c] = *(const float4*)(Kp + 4 * c);
    }

    // stage t-tile Q and K, transposed [k][m]
    {
        const float* Qp = Q + (size_t)(t0 + lm) * EMB + h * HD + lk;
        const float* Kp = K + (size_t)(t0 + lm) * EMB + h * HD + lk;
#pragma unroll
        for (int it = 0; it < 4; ++it) {
            float4 a = *(const float4*)(Qp + 4 * it);
            QT[lk + 4 * it + 0][lm] = a.x;
            QT[lk + 4 * it + 1][lm] = a.y;
            QT[lk + 4 * it + 2][lm] = a.z;
            QT[lk + 4 * it + 3][lm] = a.w;
            float4 b = *(const float4*)(Kp + 4 * it);
            KT[lk + 4 * it + 0][lm] = b.x;
            KT[lk + 4 * it + 1][lm] = b.y;
            KT[lk + 4 * it + 2][lm] = b.z;
            KT[lk + 4 * it + 3][lm] = b.w;
        }
    }

    float rm[4], rden[4], acc[4][4];
#pragma unroll
    for (int i = 0; i < 4; ++i) {
        rm[i] = -1e30f;
        rden[i] = 0.f;
#pragma unroll
        for (int j = 0; j < 4; ++j) acc[i][j] = 0.f;
    }

    for (int cp = cp_start; cp < 5; ++cp) {
        __syncthreads();   // b1: prev PV reads of Bp done (and tile staging visible on first iter)
        // write K-pair transposed [k][s_loc]
#pragma unroll
        for (int c = 0; c < 8; ++c) {
            Bc[sc + 4 * c + 0][sr] = kr[c].x;
            Bc[sc + 4 * c + 1][sr] = kr[c].y;
            Bc[sc + 4 * c + 2][sr] = kr[c].z;
            Bc[sc + 4 * c + 3][sr] = kr[c].w;
        }
        __syncthreads();   // b2

        // issue Q-pair loads (current pair); latency hides under M1
        {
            int srow = s0 + sr; srow = srow < 0 ? 0 : srow;
            const float* Qp = Q + (size_t)srow * EMB + h * HD + sc;
#pragma unroll
            for (int c = 0; c < 8; ++c) qr[c] = *(const float4*)(Qp + 4 * c);
        }

        // M1[i][j] = Q[t0+tm+i] . K[s0 + col(j)]
        float m1[4][8] = {};
#pragma unroll 8
        for (int k = 0; k < 64; ++k) {
            const float4 a4 = *(const float4*)&QT[k][tm];
            const float4 b0 = *(const float4*)&Bc[k][tn4];
            const float4 b1 = *(const float4*)&Bc[k][tn4 + 64];
            const float av[4] = {a4.x, a4.y, a4.z, a4.w};
            const float bv[8] = {b0.x, b0.y, b0.z, b0.w, b1.x, b1.y, b1.z, b1.w};
#pragma unroll
            for (int i = 0; i < 4; ++i)
#pragma unroll
                for (int j = 0; j < 8; ++j)
                    m1[i][j] += av[i] * bv[j];
        }
        __syncthreads();   // b3: M1 reads of Bc done

        // write Q-pair transposed
#pragma unroll
        for (int c = 0; c < 8; ++c) {
            Bc[sc + 4 * c + 0][sr] = qr[c].x;
            Bc[sc + 4 * c + 1][sr] = qr[c].y;
            Bc[sc + 4 * c + 2][sr] = qr[c].z;
            Bc[sc + 4 * c + 3][sr] = qr[c].w;
        }
        __syncthreads();   // b4

        // issue next K-pair loads; latency hides under M2+PV
        if (cp < 4) {
            int srow = s0 + 128 + sr; srow = srow < 0 ? 0 : srow;
            const float* Kp = K + (size_t)srow * EMB + h * HD + sc;
#pragma unroll
            for (int c = 0; c < 8; ++c) kr[c] = *(const float4*)(Kp + 4 * c);
        }

        // M2[i][j] = K[t0+tm+i] . Q[s0 + col(j)]
        float m2[4][8] = {};
#pragma unroll 8
        for (int k = 0; k < 64; ++k) {
            const float4 a4 = *(const float4*)&KT[k][tm];
            const float4 b0 = *(const float4*)&Bc[k][tn4];
            const float4 b1 = *(const float4*)&Bc[k][tn4 + 64];
            const float av[4] = {a4.x, a4.y, a4.z, a4.w};
            const float bv[8] = {b0.x, b0.y, b0.z, b0.w, b1.x, b1.y, b1.z, b1.w};
#pragma unroll
            for (int i = 0; i < 4; ++i)
#pragma unroll
                for (int j = 0; j < 8; ++j)
                    m2[i][j] += av[i] * bv[j];
        }

        // logits + masks (note: s can be < 0 for the left-edge pair)
        const int i0 = s0 + tn4;
        const int i0c = i0 < 0 ? 0 : i0;
        const float4 db0 = *(const float4*)&d_bias[h * T_LEN + i0c];
        const float4 db1 = *(const float4*)&d_bias[h * T_LEN + s0 + 64 + tn4];
        const float dbv[8] = {db0.x, db0.y, db0.z, db0.w, db1.x, db1.y, db1.z, db1.w};
        float l[4][8];
#pragma unroll
        for (int i = 0; i < 4; ++i) {
            const int t = t0 + tm + i;
#pragma unroll
            for (int j = 0; j < 8; ++j) {
                const int s = s0 + ((j < 4) ? (tn4 + j) : (tn4 + j + 60));
                const float lv = w_std * m1[i][j] + w_rec * m2[i][j] + w_disc * dbv[j];
                const bool valid = (s >= 0) && (s <= t) && (s >= t - WIN);
                l[i][j] = valid ? lv : -1e30f;
            }
        }
        // online softmax: row max across 8 own cols + 16 col-groups
#pragma unroll
        for (int i = 0; i < 4; ++i) {
            float cmx = fmaxf(fmaxf(fmaxf(l[i][0], l[i][1]), fmaxf(l[i][2], l[i][3])),
                              fmaxf(fmaxf(l[i][4], l[i][5]), fmaxf(l[i][6], l[i][7])));
#pragma unroll
            for (int off = 1; off < 16; off <<= 1) cmx = fmaxf(cmx, __shfl_xor(cmx, off));
            const float nm = fmaxf(rm[i], cmx);
            const float f = __expf(rm[i] - nm);
            float cs = 0.f;
#pragma unroll
            for (int j = 0; j < 8; ++j) {
                const float p = __expf(l[i][j] - nm);
                l[i][j] = p;
                cs += p;
            }
#pragma unroll
            for (int off = 1; off < 16; off <<= 1) cs += __shfl_xor(cs, off);
            rden[i] = rden[i] * f + cs;
            rm[i] = nm;
#pragma unroll
            for (int j = 0; j < 4; ++j) acc[i][j] *= f;
            if (cg == 0) cmf[cp][tm + i] = nm;
            // compact store: row-relative col index j = (cp<<7) + half*64 + tn4
            float* prow = &Pb[((size_t)(h * T_LEN + t0 + tm + i)) * PBW + (cp << 7)];
            *(float4*)&prow[tn4]      = make_float4(l[i][0], l[i][1], l[i][2], l[i][3]);
            *(float4*)&prow[64 + tn4] = make_float4(l[i][4], l[i][5], l[i][6], l[i][7]);
        }
        __syncthreads();   // b5: M2 reads of Bc done

        // scatter P^T into Bp[k][m] as float4 (k = s-local col)
#pragma unroll
        for (int j = 0; j < 4; ++j) {
            *(float4*)&Bp[(tn4 + j) * 68 + tm] =
                make_float4(l[0][j], l[1][j], l[2][j], l[3][j]);
            *(float4*)&Bp[(tn4 + j + 64) * 68 + tm] =
                make_float4(l[0][j + 4], l[1][j + 4], l[2][j + 4], l[3][j + 4]);
        }
        __syncthreads();   // b6

        // ctx += P @ V, V straight from global (L1/L2-hot chunk)
#pragma unroll 8
        for (int k = 0; k < 128; ++k) {
            const float4 av = *(const float4*)&Bp[k * 68 + tm];
            int vrow = s0 + k; vrow = vrow < 0 ? 0 : vrow;
            const float4 bv = *(const float4*)&V[(size_t)vrow * EMB + h * HD + tn4];
            acc[0][0] += av.x * bv.x; acc[0][1] += av.x * bv.y; acc[0][2] += av.x * bv.z; acc[0][3] += av.x * bv.w;
            acc[1][0] += av.y * bv.x; acc[1][1] += av.y * bv.y; acc[1][2] += av.y * bv.z; acc[1][3] += av.y * bv.w;
            acc[2][0] += av.z * bv.x; acc[2][1] += av.z * bv.y; acc[2][2] += av.z * bv.z; acc[2][3] += av.z * bv.w;
            acc[3][0] += av.w * bv.x; acc[3][1] += av.w * bv.y; acc[3][2] += av.w * bv.z; acc[3][3] += av.w * bv.w;
        }
        s0 += 128;
    }

    // ---- epilogue: ctx + per-pair rescale factors (no full-row output here) ----
    float idv[4];
#pragma unroll
    for (int i = 0; i < 4; ++i) {
        idv[i] = 1.0f / rden[i];
        *(float4*)&ctx[(size_t)(t0 + tm + i) * EMB + h * HD + tn4] =
            make_float4(acc[i][0] * idv[i], acc[i][1] * idv[i], acc[i][2] * idv[i], acc[i][3] * idv[i]);
    }
    if (cg == 0) {
#pragma unroll
        for (int i = 0; i < 4; ++i) {
            rmf[tm + i] = rm[i];
            idvf[tm + i] = idv[i];
        }
    }
    __syncthreads();
    // Fb[h][t][cp] = exp(m_cp - m_final) / den   (320 scalars per block)
    for (int idx = tid; idx < 320; idx += 256) {
        const int c = idx >> 6, r = idx & 63;
        const float fct = (c >= cp_start) ? __expf(cmf[c][r] - rmf[r]) * idvf[r] : 0.f;
        Fb[((size_t)(h * T_LEN + t0 + r)) * 5 + c] = fct;
    }
}

// ---------------- expand: stream full attn rows from compact band (write-BW-bound)
__global__ __launch_bounds__(256) void attn_expand_kernel(const float* __restrict__ Pb,
                                                          const float* __restrict__ Fb,
                                                          float* __restrict__ attn) {
    const int t = blockIdx.x;
    const int h = blockIdx.y;
    const int base = (t & ~63) - 576;   // col = base + j
    const float* prow = Pb + ((size_t)(h * T_LEN + t)) * PBW;
    const float* frow = Fb + ((size_t)(h * T_LEN + t)) * 5;
    float f[5];
#pragma unroll
    for (int c = 0; c < 5; ++c) f[c] = frow[c];
    float* arow = attn + ((size_t)(h * T_LEN + t)) * T_LEN;
    for (int i4 = threadIdx.x << 2; i4 < T_LEN; i4 += 1024) {
        const int j = i4 - base;
        float4 v = make_float4(0.f, 0.f, 0.f, 0.f);
        if (j >= 0 && j < PBW) {
            const float4 p = *(const float4*)&prow[j];
            const float ff = f[j >> 7];
            v = make_float4(p.x * ff, p.y * ff, p.z * ff, p.w * ff);
        }
        *(float4*)&arow[i4] = v;
    }
}

extern "C" void kernel_launch(void* const* d_in, const int* in_sizes, int n_in,
                              void* d_out, int out_size, void* d_ws, size_t ws_size,
                              hipStream_t stream) {
    const float* x     = (const float*)d_in[0];
    const float* Wq    = (const float*)d_in[1];
    const float* Wk    = (const float*)d_in[2];
    const float* Wv    = (const float*)d_in[3];
    const float* Wo    = (const float*)d_in[4];
    const float* gates = (const float*)d_in[5];
    const float* u     = (const float*)d_in[6];

    float* out  = (float*)d_out;                       // [T, E]
    float* attn = out + (size_t)T_LEN * EMB;           // [H, T, T]

    float* ws = (float*)d_ws;
    float* Qb = ws;
    float* Kb = Qb + (size_t)T_LEN * EMB;
    float* Vb = Kb + (size_t)T_LEN * EMB;
    float* Cb = Vb + (size_t)T_LEN * EMB;
    float* Db = Cb + (size_t)T_LEN * EMB;              // d bias [H, T]
    float* Pb = Db + (size_t)NH * T_LEN;               // compact band p [H, T, 640]
    float* Fb = Pb + (size_t)NH * T_LEN * PBW;         // per-pair factors [H, T, 5]

    gemm3_f32<<<dim3(EMB / GBN, T_LEN / GBM, 3), 256, 0, stream>>>(
        x, Wq, Wk, Wv, Qb, Kb, Vb, T_LEN, EMB, EMB);
    dbias_kernel<<<NH, 256, 0, stream>>>(Kb, u, Db);

    attn_band_kernel<<<dim3(T_LEN / 64, NH), 256, 0, stream>>>(Qb, Kb, Vb, Db, gates,
                                                               Pb, Fb, Cb);
    attn_expand_kernel<<<dim3(T_LEN, NH), 256, 0, stream>>>(Pb, Fb, attn);

    gemm3_f32<<<dim3(EMB / GBN, T_LEN / GBM, 1), 256, 0, stream>>>(
        Cb, Wo, Wo, Wo, out, out, out, T_LEN, EMB, EMB);
}

// Round 7
// 1404.306 us; speedup vs baseline: 1.0675x; 1.0308x over previous
//
#include <hip/hip_runtime.h>
#include <cstddef>

#define T_LEN 4096
#define EMB 768
#define NH 12
#define HD 64
#define WIN 512
#define PBW 640   // compact band width per row (5 pairs x 128)

#define GBM 128
#define GBN 128
#define GBK 16

// ---------------- 128x128 f32 GEMM block body: C[4096,768] = A[4096,768] @ B[768,768].
// 8x8 microtile, register-prefetch double buffer. Called by the fused kernels.
__device__ __forceinline__ void gemm_128(const float* __restrict__ A,
                                         const float* __restrict__ B,
                                         float* __restrict__ C,
                                         int bm, int bn, int tid) {
    __shared__ float As[GBK][GBM + 4];   // A transposed: [k][m]
    __shared__ float Bs[GBK][GBN + 4];   // B row-major:  [k][n]

    const int ty = (tid >> 4) << 2;
    const int tx = (tid & 15) << 2;

    const int ar = tid >> 1;
    const int ac = (tid & 1) << 3;
    const int br = tid >> 4;
    const int bc = (tid & 15) << 3;

    float acc[8][8] = {};

    float4 pa0 = *(const float4*)&A[(size_t)(bm + ar) * EMB + ac];
    float4 pa1 = *(const float4*)&A[(size_t)(bm + ar) * EMB + ac + 4];
    float4 pb0 = *(const float4*)&B[(size_t)br * EMB + bn + bc];
    float4 pb1 = *(const float4*)&B[(size_t)br * EMB + bn + bc + 4];

    for (int k0 = 0; k0 < EMB; k0 += GBK) {
        As[ac + 0][ar] = pa0.x; As[ac + 1][ar] = pa0.y; As[ac + 2][ar] = pa0.z; As[ac + 3][ar] = pa0.w;
        As[ac + 4][ar] = pa1.x; As[ac + 5][ar] = pa1.y; As[ac + 6][ar] = pa1.z; As[ac + 7][ar] = pa1.w;
        *(float4*)&Bs[br][bc]     = pb0;
        *(float4*)&Bs[br][bc + 4] = pb1;
        __syncthreads();
        if (k0 + GBK < EMB) {
            pa0 = *(const float4*)&A[(size_t)(bm + ar) * EMB + k0 + GBK + ac];
            pa1 = *(const float4*)&A[(size_t)(bm + ar) * EMB + k0 + GBK + ac + 4];
            pb0 = *(const float4*)&B[(size_t)(k0 + GBK + br) * EMB + bn + bc];
            pb1 = *(const float4*)&B[(size_t)(k0 + GBK + br) * EMB + bn + bc + 4];
        }
#pragma unroll
        for (int k = 0; k < GBK; ++k) {
            const float4 a0v = *(const float4*)&As[k][ty];
            const float4 a1v = *(const float4*)&As[k][ty + 64];
            const float4 b0v = *(const float4*)&Bs[k][tx];
            const float4 b1v = *(const float4*)&Bs[k][tx + 64];
            const float av[8] = {a0v.x, a0v.y, a0v.z, a0v.w, a1v.x, a1v.y, a1v.z, a1v.w};
            const float bv[8] = {b0v.x, b0v.y, b0v.z, b0v.w, b1v.x, b1v.y, b1v.z, b1v.w};
#pragma unroll
            for (int i = 0; i < 8; ++i)
#pragma unroll
                for (int j = 0; j < 8; ++j)
                    acc[i][j] += av[i] * bv[j];
        }
        __syncthreads();
    }
#pragma unroll
    for (int i = 0; i < 8; ++i) {
        const int r = bm + ty + ((i < 4) ? i : (60 + i));
        *(float4*)&C[(size_t)r * EMB + bn + tx]      = make_float4(acc[i][0], acc[i][1], acc[i][2], acc[i][3]);
        *(float4*)&C[(size_t)r * EMB + bn + tx + 64] = make_float4(acc[i][4], acc[i][5], acc[i][6], acc[i][7]);
    }
}

// ---------------- fused: QKV projections (576 blocks) + attn out-of-band zero-fill (192 blocks).
// The memory-bound zero streaming overlaps the VALU-bound GEMM on-chip.
__global__ __launch_bounds__(256) void qkv_zero_kernel(const float* __restrict__ x,
                                                       const float* __restrict__ Wq,
                                                       const float* __restrict__ Wk,
                                                       const float* __restrict__ Wv,
                                                       float* __restrict__ Qb,
                                                       float* __restrict__ Kb,
                                                       float* __restrict__ Vb,
                                                       float* __restrict__ attn) {
    const int bid = blockIdx.x;
    const int tid = threadIdx.x;
    if (bid < 576) {
        const int z = bid / 192;
        const int r = bid % 192;
        const int bm = (r / 6) * GBM;
        const int bn = (r % 6) * GBN;
        const float* B = (z == 0) ? Wq : (z == 1) ? Wk : Wv;
        float* C = (z == 0) ? Qb : (z == 1) ? Kb : Vb;
        gemm_128(x, B, C, bm, bn, tid);
    } else {
        const int zb = bid - 576;          // 0..191
        const int rr0 = tid >> 6;          // 0..3
        const int ln = tid & 63;
        const float4 z4 = make_float4(0.f, 0.f, 0.f, 0.f);
        for (int k = 0; k < 4; ++k) {
            const int p = zb + 192 * k;    // 0..767 (h, tile) pairs
            const int h = p % NH;
            const int t0 = (p / NH) << 6;
            const int bl = (t0 >= 576) ? (t0 - 576) : 0;   // left zero bound (mult of 64)
            const int br = t0 + 64;                        // right zero start
            for (int rr = rr0; rr < 64; rr += 4) {
                float* arow = attn + ((size_t)(h * T_LEN + t0 + rr)) * T_LEN;
                for (int c = ln << 2; c < bl; c += 256)
                    *(float4*)&arow[c] = z4;
                for (int c = br + (ln << 2); c < T_LEN; c += 256)
                    *(float4*)&arow[c] = z4;
            }
        }
    }
}

// ---------------- discoverability bias: d[h][t] = K_h[t]·u_h − mean
__global__ __launch_bounds__(256) void dbias_kernel(const float* __restrict__ K,
                                                    const float* __restrict__ u,
                                                    float* __restrict__ d_bias) {
    const int h = blockIdx.x;
    const int tid = threadIdx.x;
    __shared__ __align__(16) float us[HD];
    __shared__ float dr[T_LEN];
    __shared__ float red[256];
    if (tid < HD) us[tid] = u[h * HD + tid];
    __syncthreads();
    const float4* u4 = (const float4*)us;
    float lsum = 0.f;
    for (int t = tid; t < T_LEN; t += 256) {
        const float4* Kp = (const float4*)&K[(size_t)t * EMB + h * HD];
        float acc = 0.f;
#pragma unroll
        for (int i = 0; i < HD / 4; ++i) {
            float4 k4 = Kp[i];
            float4 uu = u4[i];
            acc += k4.x * uu.x + k4.y * uu.y + k4.z * uu.z + k4.w * uu.w;
        }
        dr[t] = acc;
        lsum += acc;
    }
    red[tid] = lsum;
    __syncthreads();
    for (int off = 128; off > 0; off >>= 1) {
        if (tid < off) red[tid] += red[tid + off];
        __syncthreads();
    }
    const float mean = red[0] * (1.0f / (float)T_LEN);
    __syncthreads();
    for (int t = tid; t < T_LEN; t += 256) {
        d_bias[h * T_LEN + t] = dr[t] - mean;
    }
}

// ---------------- banded attention, pair-chunks (128 cols), flash softmax.
// Stores p COMPACTLY into Pb[h][t][640] (pair-local max scaling); per-pair rescale
// factors exp(m_pair - m_final)/den into Fb[h][t][5]. ctx via P@V with V from global.
__global__ __launch_bounds__(256) void attn_band_kernel(const float* __restrict__ Q,
                                                        const float* __restrict__ K,
                                                        const float* __restrict__ V,
                                                        const float* __restrict__ d_bias,
                                                        const float* __restrict__ gates,
                                                        float* __restrict__ Pb,
                                                        float* __restrict__ Fb,
                                                        float* __restrict__ ctx) {
    const int t0  = blockIdx.x << 6;
    const int h   = blockIdx.y;
    const int tid = threadIdx.x;
    const int cg  = tid & 15;          // col group 0..15
    const int tm  = (tid >> 4) << 2;   // row base 0..60
    const int tn4 = cg << 2;           // col base within each 64-half

    const int lm = tid >> 2;           // tile staging: row 0..63
    const int lk = (tid & 3) << 4;     // tile staging: col base {0,16,32,48}
    const int sr = tid >> 1;           // pair staging: row 0..127
    const int sc = (tid & 1) << 5;     // pair staging: col base {0,32}

    __shared__ __align__(16) float QT[64][68];   // Q tile transposed [k][m]
    __shared__ __align__(16) float KT[64][68];   // K tile transposed [k][m]
    __shared__ __align__(16) float Bc[64][136];  // K-pair / Q-pair transposed; aliased as PT[128][68]
    __shared__ float cmf[5][64];                 // per-pair per-row running max
    __shared__ float rmf[64], idvf[64];
    float* __restrict__ Bp = &Bc[0][0];

    // per-head gate softmax (fold 1/sqrt(64) into w_std/w_rec)
    const float g0 = gates[h * 3 + 0];
    const float g1 = gates[h * 3 + 1];
    const float g2 = gates[h * 3 + 2];
    const float gm = fmaxf(g0, fmaxf(g1, g2));
    const float e0 = __expf(g0 - gm), e1 = __expf(g1 - gm), e2 = __expf(g2 - gm);
    const float gi = 1.0f / (e0 + e1 + e2);
    const float w_std = e0 * gi * 0.125f;
    const float w_rec = e1 * gi * 0.125f;
    const float w_disc = e2 * gi;

    const int cp_start = (t0 >= 576) ? 0 : ((576 - t0) >> 7);
    int s0 = t0 - 576 + (cp_start << 7);       // >= -64, multiple of 64

    // prefetch first K-pair
    float4 kr[8], qr[8];
    {
        int srow = s0 + sr; srow = srow < 0 ? 0 : srow;
        const float* Kp = K + (size_t)srow * EMB + h * HD + sc;
#pragma unroll
        for (int c = 0; c < 8; ++c) kr[c] = *(const float4*)(Kp + 4 * c);
    }

    // stage t-tile Q and K, transposed [k][m]
    {
        const float* Qp = Q + (size_t)(t0 + lm) * EMB + h * HD + lk;
        const float* Kp = K + (size_t)(t0 + lm) * EMB + h * HD + lk;
#pragma unroll
        for (int it = 0; it < 4; ++it) {
            float4 a = *(const float4*)(Qp + 4 * it);
            QT[lk + 4 * it + 0][lm] = a.x;
            QT[lk + 4 * it + 1][lm] = a.y;
            QT[lk + 4 * it + 2][lm] = a.z;
            QT[lk + 4 * it + 3][lm] = a.w;
            float4 b = *(const float4*)(Kp + 4 * it);
            KT[lk + 4 * it + 0][lm] = b.x;
            KT[lk + 4 * it + 1][lm] = b.y;
            KT[lk + 4 * it + 2][lm] = b.z;
            KT[lk + 4 * it + 3][lm] = b.w;
        }
    }

    float rm[4], rden[4], acc[4][4];
#pragma unroll
    for (int i = 0; i < 4; ++i) {
        rm[i] = -1e30f;
        rden[i] = 0.f;
#pragma unroll
        for (int j = 0; j < 4; ++j) acc[i][j] = 0.f;
    }

    for (int cp = cp_start; cp < 5; ++cp) {
        __syncthreads();   // b1: prev PV reads of Bp done
        // write K-pair transposed [k][s_loc]
#pragma unroll
        for (int c = 0; c < 8; ++c) {
            Bc[sc + 4 * c + 0][sr] = kr[c].x;
            Bc[sc + 4 * c + 1][sr] = kr[c].y;
            Bc[sc + 4 * c + 2][sr] = kr[c].z;
            Bc[sc + 4 * c + 3][sr] = kr[c].w;
        }
        __syncthreads();   // b2

        // issue Q-pair loads (current pair); latency hides under M1
        {
            int srow = s0 + sr; srow = srow < 0 ? 0 : srow;
            const float* Qp = Q + (size_t)srow * EMB + h * HD + sc;
#pragma unroll
            for (int c = 0; c < 8; ++c) qr[c] = *(const float4*)(Qp + 4 * c);
        }

        // M1[i][j] = Q[t0+tm+i] . K[s0 + col(j)]
        float m1[4][8] = {};
#pragma unroll 8
        for (int k = 0; k < 64; ++k) {
            const float4 a4 = *(const float4*)&QT[k][tm];
            const float4 b0 = *(const float4*)&Bc[k][tn4];
            const float4 b1 = *(const float4*)&Bc[k][tn4 + 64];
            const float av[4] = {a4.x, a4.y, a4.z, a4.w};
            const float bv[8] = {b0.x, b0.y, b0.z, b0.w, b1.x, b1.y, b1.z, b1.w};
#pragma unroll
            for (int i = 0; i < 4; ++i)
#pragma unroll
                for (int j = 0; j < 8; ++j)
                    m1[i][j] += av[i] * bv[j];
        }
        __syncthreads();   // b3

        // write Q-pair transposed
#pragma unroll
        for (int c = 0; c < 8; ++c) {
            Bc[sc + 4 * c + 0][sr] = qr[c].x;
            Bc[sc + 4 * c + 1][sr] = qr[c].y;
            Bc[sc + 4 * c + 2][sr] = qr[c].z;
            Bc[sc + 4 * c + 3][sr] = qr[c].w;
        }
        __syncthreads();   // b4

        // issue next K-pair loads; latency hides under M2+PV
        if (cp < 4) {
            int srow = s0 + 128 + sr; srow = srow < 0 ? 0 : srow;
            const float* Kp = K + (size_t)srow * EMB + h * HD + sc;
#pragma unroll
            for (int c = 0; c < 8; ++c) kr[c] = *(const float4*)(Kp + 4 * c);
        }

        // M2[i][j] = K[t0+tm+i] . Q[s0 + col(j)]
        float m2[4][8] = {};
#pragma unroll 8
        for (int k = 0; k < 64; ++k) {
            const float4 a4 = *(const float4*)&KT[k][tm];
            const float4 b0 = *(const float4*)&Bc[k][tn4];
            const float4 b1 = *(const float4*)&Bc[k][tn4 + 64];
            const float av[4] = {a4.x, a4.y, a4.z, a4.w};
            const float bv[8] = {b0.x, b0.y, b0.z, b0.w, b1.x, b1.y, b1.z, b1.w};
#pragma unroll
            for (int i = 0; i < 4; ++i)
#pragma unroll
                for (int j = 0; j < 8; ++j)
                    m2[i][j] += av[i] * bv[j];
        }

        // logits + masks (s can be < 0 for the left-edge pair)
        const int i0 = s0 + tn4;
        const int i0c = i0 < 0 ? 0 : i0;
        const float4 db0 = *(const float4*)&d_bias[h * T_LEN + i0c];
        const float4 db1 = *(const float4*)&d_bias[h * T_LEN + s0 + 64 + tn4];
        const float dbv[8] = {db0.x, db0.y, db0.z, db0.w, db1.x, db1.y, db1.z, db1.w};
        float l[4][8];
#pragma unroll
        for (int i = 0; i < 4; ++i) {
            const int t = t0 + tm + i;
#pragma unroll
            for (int j = 0; j < 8; ++j) {
                const int s = s0 + ((j < 4) ? (tn4 + j) : (tn4 + j + 60));
                const float lv = w_std * m1[i][j] + w_rec * m2[i][j] + w_disc * dbv[j];
                const bool valid = (s >= 0) && (s <= t) && (s >= t - WIN);
                l[i][j] = valid ? lv : -1e30f;
            }
        }
        // online softmax
#pragma unroll
        for (int i = 0; i < 4; ++i) {
            float cmx = fmaxf(fmaxf(fmaxf(l[i][0], l[i][1]), fmaxf(l[i][2], l[i][3])),
                              fmaxf(fmaxf(l[i][4], l[i][5]), fmaxf(l[i][6], l[i][7])));
#pragma unroll
            for (int off = 1; off < 16; off <<= 1) cmx = fmaxf(cmx, __shfl_xor(cmx, off));
            const float nm = fmaxf(rm[i], cmx);
            const float f = __expf(rm[i] - nm);
            float cs = 0.f;
#pragma unroll
            for (int j = 0; j < 8; ++j) {
                const float p = __expf(l[i][j] - nm);
                l[i][j] = p;
                cs += p;
            }
#pragma unroll
            for (int off = 1; off < 16; off <<= 1) cs += __shfl_xor(cs, off);
            rden[i] = rden[i] * f + cs;
            rm[i] = nm;
#pragma unroll
            for (int j = 0; j < 4; ++j) acc[i][j] *= f;
            if (cg == 0) cmf[cp][tm + i] = nm;
            // compact store: row-relative col index j = (cp<<7) + half*64 + tn4
            float* prow = &Pb[((size_t)(h * T_LEN + t0 + tm + i)) * PBW + (cp << 7)];
            *(float4*)&prow[tn4]      = make_float4(l[i][0], l[i][1], l[i][2], l[i][3]);
            *(float4*)&prow[64 + tn4] = make_float4(l[i][4], l[i][5], l[i][6], l[i][7]);
        }
        __syncthreads();   // b5

        // scatter P^T into Bp[k][m] as float4 (k = s-local col)
#pragma unroll
        for (int j = 0; j < 4; ++j) {
            *(float4*)&Bp[(tn4 + j) * 68 + tm] =
                make_float4(l[0][j], l[1][j], l[2][j], l[3][j]);
            *(float4*)&Bp[(tn4 + j + 64) * 68 + tm] =
                make_float4(l[0][j + 4], l[1][j + 4], l[2][j + 4], l[3][j + 4]);
        }
        __syncthreads();   // b6

        // ctx += P @ V, V straight from global (L1/L2-hot chunk)
#pragma unroll 8
        for (int k = 0; k < 128; ++k) {
            const float4 av = *(const float4*)&Bp[k * 68 + tm];
            int vrow = s0 + k; vrow = vrow < 0 ? 0 : vrow;
            const float4 bv = *(const float4*)&V[(size_t)vrow * EMB + h * HD + tn4];
            acc[0][0] += av.x * bv.x; acc[0][1] += av.x * bv.y; acc[0][2] += av.x * bv.z; acc[0][3] += av.x * bv.w;
            acc[1][0] += av.y * bv.x; acc[1][1] += av.y * bv.y; acc[1][2] += av.y * bv.z; acc[1][3] += av.y * bv.w;
            acc[2][0] += av.z * bv.x; acc[2][1] += av.z * bv.y; acc[2][2] += av.z * bv.z; acc[2][3] += av.z * bv.w;
            acc[3][0] += av.w * bv.x; acc[3][1] += av.w * bv.y; acc[3][2] += av.w * bv.z; acc[3][3] += av.w * bv.w;
        }
        s0 += 128;
    }

    // ---- epilogue: ctx + per-pair rescale factors ----
    float idv[4];
#pragma unroll
    for (int i = 0; i < 4; ++i) {
        idv[i] = 1.0f / rden[i];
        *(float4*)&ctx[(size_t)(t0 + tm + i) * EMB + h * HD + tn4] =
            make_float4(acc[i][0] * idv[i], acc[i][1] * idv[i], acc[i][2] * idv[i], acc[i][3] * idv[i]);
    }
    if (cg == 0) {
#pragma unroll
        for (int i = 0; i < 4; ++i) {
            rmf[tm + i] = rm[i];
            idvf[tm + i] = idv[i];
        }
    }
    __syncthreads();
    // Fb[h][t][cp] = exp(m_cp - m_final) / den
    for (int idx = tid; idx < 320; idx += 256) {
        const int c = idx >> 6, r = idx & 63;
        const float fct = (c >= cp_start) ? __expf(cmf[c][r] - rmf[r]) * idvf[r] : 0.f;
        Fb[((size_t)(h * T_LEN + t0 + r)) * 5 + c] = fct;
    }
}

// ---------------- fused: Wo projection (192 blocks) + band expand (12288 blocks).
// Expand writes ONLY the band window; zeros were streamed by qkv_zero_kernel.
__global__ __launch_bounds__(256) void wo_expand_kernel(const float* __restrict__ Cb,
                                                        const float* __restrict__ Wo,
                                                        float* __restrict__ out,
                                                        const float* __restrict__ Pb,
                                                        const float* __restrict__ Fb,
                                                        float* __restrict__ attn) {
    const int bid = blockIdx.x;
    const int tid = threadIdx.x;
    if (bid < 192) {
        const int bm = (bid / 6) * GBM;
        const int bn = (bid % 6) * GBN;
        gemm_128(Cb, Wo, out, bm, bn, tid);
    } else {
        const int e = bid - 192;               // 0..12287
        const int h = e / 1024;
        const int t = ((e % 1024) << 2) + (tid >> 6);   // 4 rows per block
        const int ln = tid & 63;
        const int base = (t & ~63) - 576;      // col = base + j
        const int j_lo = (base < 0) ? -base : 0;   // mult of 64
        const float* prow = Pb + ((size_t)(h * T_LEN + t)) * PBW;
        const float* frow = Fb + ((size_t)(h * T_LEN + t)) * 5;
        const float f0 = frow[0], f1 = frow[1], f2 = frow[2], f3 = frow[3], f4 = frow[4];
        float* arow = attn + ((size_t)(h * T_LEN + t)) * T_LEN;
        for (int j4 = j_lo + (ln << 2); j4 < PBW; j4 += 256) {
            const float4 p = *(const float4*)&prow[j4];
            const float ff = (j4 < 128) ? f0 : (j4 < 256) ? f1 : (j4 < 384) ? f2
                           : (j4 < 512) ? f3 : f4;
            *(float4*)&arow[base + j4] = make_float4(p.x * ff, p.y * ff, p.z * ff, p.w * ff);
        }
    }
}

extern "C" void kernel_launch(void* const* d_in, const int* in_sizes, int n_in,
                              void* d_out, int out_size, void* d_ws, size_t ws_size,
                              hipStream_t stream) {
    const float* x     = (const float*)d_in[0];
    const float* Wq    = (const float*)d_in[1];
    const float* Wk    = (const float*)d_in[2];
    const float* Wv    = (const float*)d_in[3];
    const float* Wo    = (const float*)d_in[4];
    const float* gates = (const float*)d_in[5];
    const float* u     = (const float*)d_in[6];

    float* out  = (float*)d_out;                       // [T, E]
    float* attn = out + (size_t)T_LEN * EMB;           // [H, T, T]

    float* ws = (float*)d_ws;
    float* Qb = ws;
    float* Kb = Qb + (size_t)T_LEN * EMB;
    float* Vb = Kb + (size_t)T_LEN * EMB;
    float* Cb = Vb + (size_t)T_LEN * EMB;
    float* Db = Cb + (size_t)T_LEN * EMB;              // d bias [H, T]
    float* Pb = Db + (size_t)NH * T_LEN;               // compact band p [H, T, 640]
    float* Fb = Pb + (size_t)NH * T_LEN * PBW;         // per-pair factors [H, T, 5]

    // QKV projections + out-of-band zero streaming, overlapped in one launch
    qkv_zero_kernel<<<768, 256, 0, stream>>>(x, Wq, Wk, Wv, Qb, Kb, Vb, attn);
    dbias_kernel<<<NH, 256, 0, stream>>>(Kb, u, Db);

    attn_band_kernel<<<dim3(T_LEN / 64, NH), 256, 0, stream>>>(Qb, Kb, Vb, Db, gates,
                                                               Pb, Fb, Cb);

    // Wo projection + band expand, overlapped in one launch
    wo_expand_kernel<<<192 + 12288, 256, 0, stream>>>(Cb, Wo, out, Pb, Fb, attn);
}